// Round 3
// baseline (660.988 us; speedup 1.0000x reference)
//
#include <hip/hip_runtime.h>
#include <hip/hip_bf16.h>
#include <stdint.h>

// Problem constants (fixed by setup_inputs)
#define M_TOT 8192
#define N_TOT 4096
#define K_TOT 4096
#define GROUP 128

// Tile config: 128x128 tile, 4 waves (2x2), each wave 64x64 via 4x4 frags of 16x16x32
#define BM 128
#define BN 128
#define BK 64
#define BKP 72  // padded k-stride (+16B): fragment reads land 2-way on banks (free, m136)

// NOTE (round 2 lesson): reference arrays are float16 -> harness exchanges them
// as FLOAT32 ("else float*" rule). x/scales/bias are const float*, d_out is float*.

using f32x4  = __attribute__((ext_vector_type(4))) float;
using bf16x8 = __attribute__((ext_vector_type(8))) __bf16;

__global__ __launch_bounds__(256) void gptq_gemm(
    const float* __restrict__ x,       // [M, K] f32 (fp16-upcast)
    const int*   __restrict__ qweight, // [K/8, N]
    const int*   __restrict__ qzeros,  // [G, N/8]
    const float* __restrict__ scales,  // [G, N] f32
    const int*   __restrict__ g_idx,   // [K]
    const float* __restrict__ bias,    // [N] f32
    float* __restrict__ out)           // [M, N] f32
{
    __shared__ __align__(16) unsigned short As[BM * BKP];  // bf16 [BM][BKP]
    __shared__ __align__(16) unsigned short Bt[BN * BKP];  // bf16 [BN][BKP] (k contiguous)

    const int tid  = threadIdx.x;
    const int wave = tid >> 6;
    const int lane = tid & 63;
    const int n0 = blockIdx.x * BN;
    const int m0 = blockIdx.y * BM;

    const int wm = (wave >> 1) * 64;   // wave row offset in tile
    const int wn = (wave & 1) * 64;    // wave col offset in tile

    const int l15  = lane & 15;
    const int quad = lane >> 4;        // 0..3

    f32x4 acc[4][4];
    #pragma unroll
    for (int i = 0; i < 4; ++i)
        #pragma unroll
        for (int j = 0; j < 4; ++j)
            acc[i][j] = (f32x4)0.f;

    // A staging: 1024 chunks of 8 elems; 256 threads x 4 chunks (2x float4 each)
    // B staging: 1024 int32 = 256 threads x int4 (8 k-rows x 128 n)
    const int r  = tid >> 5;           // 0..7  -> qweight sub-row (8 k's each)
    const int c4 = (tid & 31) << 2;    // 0,4,...,124 -> n offset (4 cols)

    for (int kt = 0; kt < K_TOT / BK; ++kt) {
        const int k0 = kt * BK;

        // ---- stage A: f32 global loads -> cvt bf16 -> 16B LDS writes ----
        #pragma unroll
        for (int i = 0; i < 4; ++i) {
            const int c   = tid + i * 256;            // chunk id
            const int row = c >> 3;
            const int cb  = (c & 7) << 3;             // k offset within tile (x8)
            const float* xp = x + (size_t)(m0 + row) * K_TOT + (k0 + cb);
            const float4 f0 = *(const float4*)xp;
            const float4 f1 = *(const float4*)(xp + 4);
            bf16x8 v;
            v[0] = (__bf16)f0.x; v[1] = (__bf16)f0.y;
            v[2] = (__bf16)f0.z; v[3] = (__bf16)f0.w;
            v[4] = (__bf16)f1.x; v[5] = (__bf16)f1.y;
            v[6] = (__bf16)f1.z; v[7] = (__bf16)f1.w;
            *(bf16x8*)&As[row * BKP + cb] = v;
        }

        // ---- stage B: dequant 4-bit -> bf16, transposed into LDS ----
        // BK=64 always inside one quant group (64 | 128)
        const int g = g_idx[k0];
        const int4 q = *(const int4*)&qweight[(size_t)((k0 >> 3) + r) * N_TOT + (n0 + c4)];
        const int zint = qzeros[g * (N_TOT / 8) + ((n0 + c4) >> 3)];
        const int zsh  = (c4 & 7);     // 0 or 4
        const float4 sv = *(const float4*)&scales[g * N_TOT + n0 + c4];

        #pragma unroll
        for (int dn = 0; dn < 4; ++dn) {
            const int qi  = ((const int*)&q)[dn];
            const float s = ((const float*)&sv)[dn];
            const float zs = (float)(((zint >> ((zsh + dn) * 4)) & 0xF) + 1) * s;
            bf16x8 v;
            #pragma unroll
            for (int j = 0; j < 8; ++j) {
                const float w = (float)((qi >> (4 * j)) & 0xF);
                v[j] = (__bf16)(w * s - zs);   // (w - z - 1) * s
            }
            *(bf16x8*)&Bt[(c4 + dn) * BKP + r * 8] = v;
        }

        __syncthreads();

        // ---- compute: 2 k-steps of 32 ----
        #pragma unroll
        for (int ks = 0; ks < 2; ++ks) {
            bf16x8 af[4], bfv[4];
            #pragma unroll
            for (int mt = 0; mt < 4; ++mt)
                af[mt] = *(const bf16x8*)&As[(wm + mt * 16 + l15) * BKP + ks * 32 + quad * 8];
            #pragma unroll
            for (int nt = 0; nt < 4; ++nt)
                bfv[nt] = *(const bf16x8*)&Bt[(wn + nt * 16 + l15) * BKP + ks * 32 + quad * 8];
            #pragma unroll
            for (int mt = 0; mt < 4; ++mt)
                #pragma unroll
                for (int nt = 0; nt < 4; ++nt)
                    acc[mt][nt] = __builtin_amdgcn_mfma_f32_16x16x32_bf16(
                        af[mt], bfv[nt], acc[mt][nt], 0, 0, 0);
        }
        __syncthreads();
    }

    // ---- epilogue: C/D layout col=lane&15, row=quad*4+reg (m89/m91-verified) ----
    #pragma unroll
    for (int nt = 0; nt < 4; ++nt) {
        const int col = n0 + wn + nt * 16 + l15;
        const float bv = bias[col];
        #pragma unroll
        for (int mt = 0; mt < 4; ++mt) {
            const int rowb = m0 + wm + mt * 16 + quad * 4;
            #pragma unroll
            for (int i = 0; i < 4; ++i) {
                out[(size_t)(rowb + i) * N_TOT + col] = acc[mt][nt][i] + bv;
            }
        }
    }
}

extern "C" void kernel_launch(void* const* d_in, const int* in_sizes, int n_in,
                              void* d_out, int out_size, void* d_ws, size_t ws_size,
                              hipStream_t stream) {
    const float* x  = (const float*)d_in[0];
    const int*   qw = (const int*)d_in[1];
    const int*   qz = (const int*)d_in[2];
    const float* sc = (const float*)d_in[3];
    const int*   gi = (const int*)d_in[4];
    const float* bs = (const float*)d_in[5];
    float* out = (float*)d_out;

    dim3 grid(N_TOT / BN, M_TOT / BM);  // (32, 64)
    gptq_gemm<<<grid, dim3(256), 0, stream>>>(x, qw, qz, sc, gi, bs, out);
}